// Round 1
// 1473.217 us; speedup vs baseline: 1.2170x; 1.2170x over previous
//
#include <hip/hip_runtime.h>
#include <hip/hip_bf16.h>
#include <stdint.h>

// Problem constants (B,S,H,L) = (8, 4096, 2048, 4)
#define B_ 8
#define S_ 4096
#define H_ 2048
#define L_ 4
#define M_ (B_ * S_)   // 32768 rows
// GEMM: C[M,N] = A[M,K] * W[N,K]^T + bias, K = N = H_

typedef __attribute__((ext_vector_type(8))) __bf16 bf16x8;
typedef __attribute__((ext_vector_type(4))) float f32x4;

__device__ __forceinline__ unsigned short f32_bf16_rne(float f) {
    union { float f; unsigned int u; } v;
    v.f = f;
    unsigned int u = v.u;
    u += 0x7FFFu + ((u >> 16) & 1u);   // round-to-nearest-even
    return (unsigned short)(u >> 16);
}

__global__ void cvt_f32_to_bf16(const float4* __restrict__ in,
                                ushort4* __restrict__ out, int n4) {
    int i = blockIdx.x * blockDim.x + threadIdx.x;
    if (i < n4) {
        float4 v = in[i];
        ushort4 o;
        o.x = f32_bf16_rne(v.x);
        o.y = f32_bf16_rne(v.y);
        o.z = f32_bf16_rne(v.z);
        o.w = f32_bf16_rne(v.w);
        out[i] = o;
    }
}

// ---------------------------------------------------------------------------
// 256x256-tile, BK=64, 8-wave (2M x 4N), 8-phase schedule with counted vmcnt
// (T1 XCD swizzle + T2 LDS XOR swizzle + T3/T4 phases + T5 setprio).
//
// LDS: [buf(2)][mat A/B][256 rows][64 k] bf16 = 128 KiB. Half-tile = 128 rows.
// Staging: global_load_lds width=16, linear LDS dest (wave base + lane*16B).
//   Swizzle is applied by permuting the per-lane GLOBAL source column-chunk
//   (j ^= row&7 at 16B granularity) and the same XOR on the ds_read side.
// Schedule per K-tile kt (4 phases, each: ds_read subtile | stage 1 half |
//   s_barrier | lgkmcnt(0) | setprio(1) 16xMFMA setprio(0) | s_barrier):
//   ph0: read B(all)+A(f0,f1); stage A-lo(kt+1)
//   ph1: read A(f2,f3);        stage A-hi(kt+1), B-lo(kt+2)
//   ph2: read A(f4,f5);        stage B-hi(kt+2)
//   ph3: read A(f6,f7);        fence vmcnt(4)  (kt==30 -> vmcnt(0))
// Invariants (checked): a region is overwritten only after the barrier that
// retires its last reader; at each fence the K-tile kt+1 halves are exactly
// the ones older than the 2 youngest (= 4 loads) in flight.
// ---------------------------------------------------------------------------

#define GLDS(srcp, dstp)                                                      \
    __builtin_amdgcn_global_load_lds(                                         \
        (const __attribute__((address_space(1))) void*)(srcp),                \
        (__attribute__((address_space(3))) void*)(dstp), 16, 0, 0)

template <bool OUT_BF16>
__global__ __launch_bounds__(512, 2)
void gemm8(const unsigned short* __restrict__ A,   // M x K, bf16 bits
           const unsigned short* __restrict__ W,   // N x K, bf16 bits
           const float* __restrict__ bias,         // N
           const int* __restrict__ perm,           // S_ entries or nullptr
           void* __restrict__ outv)                // M x N
{
    constexpr int K = H_;
    constexpr int N = H_;

    __shared__ unsigned short lds[65536];  // 128 KiB

    const int tid = threadIdx.x;
    const int w   = tid >> 6;     // wave 0..7
    const int l   = tid & 63;

    // T1: XCD-aware swizzle. nwg=1024, 1024%8==0 -> simple bijective map.
    // XCD x owns wgid [x*128, x*128+128) -> one N-column (tileN==x): the 1 MB
    // W panel is L2-resident per XCD; A panels stream once via L3.
    const int bid   = blockIdx.x;
    const int wgid  = (bid & 7) * 128 + (bid >> 3);
    const int tileN = wgid >> 7;   // 0..7
    const int tileM = wgid & 127;  // 0..127

    // ---- staging source pointers (per half h, per issue i) ----
    // LDS chunk (row, j') holds global col-chunk j'^(row&7); with linear dest
    // chunk = (i*8+w)*64 + l we get row&7 == (l>>3)&7, so the source column
    // chunk is the lane constant (l&7)^((l>>3)&7).
    const int jsrc = (l & 7) ^ ((l >> 3) & 7);
    const unsigned short* aP[2][2];
    const unsigned short* bP[2][2];
#pragma unroll
    for (int h = 0; h < 2; ++h)
#pragma unroll
        for (int i = 0; i < 2; ++i) {
            int r  = h * 128 + (i * 8 + w) * 8 + (l >> 3);  // row in 256-tile
            int gm = tileM * 256 + r;
            int src;
            if (perm) {
                int b = gm >> 12;            // / S_
                int s = gm & (S_ - 1);
                src = (b << 12) + perm[s];   // gather source row
            } else {
                src = gm;
            }
            aP[h][i] = A + (size_t)src * K + jsrc * 8;
            bP[h][i] = W + (size_t)(tileN * 256 + r) * K + jsrc * 8;
        }

    unsigned short* ldsw = &lds[w * 512];  // wave-uniform dest base

#define STAGE_A(buf, half, kt0) do {                                          \
        GLDS(aP[half][0] + (kt0) * 64,                                        \
             ldsw + (buf) * 32768 + (half) * 8192);                           \
        GLDS(aP[half][1] + (kt0) * 64,                                        \
             ldsw + (buf) * 32768 + (half) * 8192 + 4096);                    \
    } while (0)
#define STAGE_B(buf, half, kt0) do {                                          \
        GLDS(bP[half][0] + (kt0) * 64,                                        \
             ldsw + (buf) * 32768 + 16384 + (half) * 8192);                   \
        GLDS(bP[half][1] + (kt0) * 64,                                        \
             ldsw + (buf) * 32768 + 16384 + (half) * 8192 + 4096);            \
    } while (0)

    // ---- fragment read addressing (T2 read-side XOR) ----
    const int lm = l & 15;
    const int wm = w >> 2;   // 0..1  M-half of tile
    const int wn = w & 3;    // 0..3  N-quarter of tile
    const int cx0 = (((l >> 4) + 0) ^ (l & 7)) * 8;   // swizzled col, ks=0
    const int cx1 = (((l >> 4) + 4) ^ (l & 7)) * 8;   // swizzled col, ks=1
    const int aO0 = (wm * 128 + lm) * 64 + cx0;
    const int aO1 = (wm * 128 + lm) * 64 + cx1;
    const int bO0 = 16384 + (wn * 64 + lm) * 64 + cx0;
    const int bO1 = 16384 + (wn * 64 + lm) * 64 + cx1;

#define LDA(bo, f, ks) (*(const bf16x8*)&lds[(bo) + ((ks) ? aO1 : aO0) + (f) * 1024])
#define LDB(bo, n, ks) (*(const bf16x8*)&lds[(bo) + ((ks) ? bO1 : bO0) + (n) * 1024])

    f32x4 acc[8][4];
#pragma unroll
    for (int i = 0; i < 8; ++i)
#pragma unroll
        for (int j2 = 0; j2 < 4; ++j2) {
            f32x4 z = {0.f, 0.f, 0.f, 0.f};
            acc[i][j2] = z;
        }

    // ---- prologue: K-tile 0 (4 halves) -> buf0; B of K-tile 1 -> buf1 ----
    STAGE_A(0, 0, 0); STAGE_A(0, 1, 0);
    STAGE_B(0, 0, 0); STAGE_B(0, 1, 0);
    STAGE_B(1, 0, 1); STAGE_B(1, 1, 1);
    asm volatile("s_waitcnt vmcnt(4)" ::: "memory");  // K-tile 0 resident
    __builtin_amdgcn_s_barrier();

#define MFMA_Q(q)                                                             \
    __builtin_amdgcn_s_setprio(1);                                            \
    _Pragma("unroll")                                                         \
    for (int n = 0; n < 4; ++n) {                                             \
        acc[2*(q)  ][n] = __builtin_amdgcn_mfma_f32_16x16x32_bf16(            \
            a0k0, bf[n][0], acc[2*(q)  ][n], 0, 0, 0);                        \
        acc[2*(q)  ][n] = __builtin_amdgcn_mfma_f32_16x16x32_bf16(            \
            a0k1, bf[n][1], acc[2*(q)  ][n], 0, 0, 0);                        \
        acc[2*(q)+1][n] = __builtin_amdgcn_mfma_f32_16x16x32_bf16(            \
            a1k0, bf[n][0], acc[2*(q)+1][n], 0, 0, 0);                        \
        acc[2*(q)+1][n] = __builtin_amdgcn_mfma_f32_16x16x32_bf16(            \
            a1k1, bf[n][1], acc[2*(q)+1][n], 0, 0, 0);                        \
    }                                                                         \
    __builtin_amdgcn_s_setprio(0);

    for (int kt = 0; kt < 32; ++kt) {
        const int bo = (kt & 1) << 15;   // current buffer, element offset
        const int cb = kt & 1;
        const int nb = cb ^ 1;
        bf16x8 bf[4][2];

        { // phase 0: B frags + A f0,f1; stage A-lo(kt+1)
            bf16x8 a0k0 = LDA(bo, 0, 0), a0k1 = LDA(bo, 0, 1);
            bf16x8 a1k0 = LDA(bo, 1, 0), a1k1 = LDA(bo, 1, 1);
#pragma unroll
            for (int n = 0; n < 4; ++n) {
                bf[n][0] = LDB(bo, n, 0);
                bf[n][1] = LDB(bo, n, 1);
            }
            if (kt < 31) STAGE_A(nb, 0, kt + 1);
            __builtin_amdgcn_s_barrier();
            asm volatile("s_waitcnt lgkmcnt(0)" ::: "memory");
            MFMA_Q(0);
            __builtin_amdgcn_s_barrier();
        }
        { // phase 1: A f2,f3; stage A-hi(kt+1), B-lo(kt+2)
            bf16x8 a0k0 = LDA(bo, 2, 0), a0k1 = LDA(bo, 2, 1);
            bf16x8 a1k0 = LDA(bo, 3, 0), a1k1 = LDA(bo, 3, 1);
            if (kt < 31) STAGE_A(nb, 1, kt + 1);
            if (kt < 30) STAGE_B(cb, 0, kt + 2);
            __builtin_amdgcn_s_barrier();
            asm volatile("s_waitcnt lgkmcnt(0)" ::: "memory");
            MFMA_Q(1);
            __builtin_amdgcn_s_barrier();
        }
        { // phase 2: A f4,f5; stage B-hi(kt+2)
            bf16x8 a0k0 = LDA(bo, 4, 0), a0k1 = LDA(bo, 4, 1);
            bf16x8 a1k0 = LDA(bo, 5, 0), a1k1 = LDA(bo, 5, 1);
            if (kt < 30) STAGE_B(cb, 1, kt + 2);
            __builtin_amdgcn_s_barrier();
            asm volatile("s_waitcnt lgkmcnt(0)" ::: "memory");
            MFMA_Q(2);
            __builtin_amdgcn_s_barrier();
        }
        { // phase 3: A f6,f7; counted fence (K-tile kt+1 becomes resident)
            bf16x8 a0k0 = LDA(bo, 6, 0), a0k1 = LDA(bo, 6, 1);
            bf16x8 a1k0 = LDA(bo, 7, 0), a1k1 = LDA(bo, 7, 1);
            if (kt < 30) {
                asm volatile("s_waitcnt vmcnt(4)" ::: "memory");
            } else if (kt == 30) {
                asm volatile("s_waitcnt vmcnt(0)" ::: "memory");
            }
            __builtin_amdgcn_s_barrier();
            asm volatile("s_waitcnt lgkmcnt(0)" ::: "memory");
            MFMA_Q(3);
            __builtin_amdgcn_s_barrier();
        }
    }

    // ---- epilogue: C/D layout col = lane&15, row = (lane>>4)*4 + reg ----
    const int orow0 = tileM * 256 + wm * 128 + (l >> 4) * 4;
    const int ocol0 = tileN * 256 + wn * 64 + lm;
    float bval[4];
#pragma unroll
    for (int n = 0; n < 4; ++n) bval[n] = bias[ocol0 + n * 16];

#pragma unroll
    for (int f = 0; f < 8; ++f) {
#pragma unroll
        for (int n = 0; n < 4; ++n) {
#pragma unroll
            for (int r = 0; r < 4; ++r) {
                int row = orow0 + f * 16 + r;
                int col = ocol0 + n * 16;
                float v = acc[f][n][r] + bval[n];
                if (OUT_BF16) {
                    ((unsigned short*)outv)[(size_t)row * N + col] = f32_bf16_rne(v);
                } else {
                    ((float*)outv)[(size_t)row * N + col] = v;
                }
            }
        }
    }
#undef LDA
#undef LDB
#undef STAGE_A
#undef STAGE_B
#undef MFMA_Q
}

extern "C" void kernel_launch(void* const* d_in, const int* in_sizes, int n_in,
                              void* d_out, int out_size, void* d_ws, size_t ws_size,
                              hipStream_t stream) {
    const float* x       = (const float*)d_in[0];  // (8,4096,2048) f32
    const float* weights = (const float*)d_in[1];  // (4,2048,2048) f32
    const float* biases  = (const float*)d_in[2];  // (4,2048) f32
    const int*   perms   = (const int*)d_in[3];    // (3,4096) i32
    float* out = (float*)d_out;

    // ws layout: P = bf16 ping buffer (128 MB), Wbf = bf16 weights (32 MB).
    // Q = low half of d_out reinterpreted as bf16 (d_out is 256 MB fp32).
    // Sequence Q -> P -> Q -> P -> d_out keeps final-layer input (P) disjoint
    // from its fp32 output (d_out).
    unsigned short* bufP = (unsigned short*)d_ws;
    unsigned short* wBf  = (unsigned short*)((char*)d_ws + (size_t)M_ * H_ * 2);
    unsigned short* bufQ = (unsigned short*)d_out;

    {
        int n4 = (L_ * H_ * H_) / 4;
        cvt_f32_to_bf16<<<(n4 + 255) / 256, 256, 0, stream>>>(
            (const float4*)weights, (ushort4*)wBf, n4);
    }
    {
        int n4 = (M_ * H_) / 4;
        cvt_f32_to_bf16<<<(n4 + 255) / 256, 256, 0, stream>>>(
            (const float4*)x, (ushort4*)bufQ, n4);
    }

    dim3 grid(1024);  // (M_/256) * (H_/256) = 128 * 8
    // layer 0: no gather
    gemm8<true ><<<grid, 512, 0, stream>>>(bufQ, wBf + 0 * (size_t)H_ * H_,
                                           biases + 0 * H_, nullptr, bufP);
    // layer 1: gather rows via perms[0]
    gemm8<true ><<<grid, 512, 0, stream>>>(bufP, wBf + 1 * (size_t)H_ * H_,
                                           biases + 1 * H_, perms + 0 * S_, bufQ);
    // layer 2: gather via perms[1]
    gemm8<true ><<<grid, 512, 0, stream>>>(bufQ, wBf + 2 * (size_t)H_ * H_,
                                           biases + 2 * H_, perms + 1 * S_, bufP);
    // layer 3: gather via perms[2], fp32 output
    gemm8<false><<<grid, 512, 0, stream>>>(bufP, wBf + 3 * (size_t)H_ * H_,
                                           biases + 3 * H_, perms + 2 * S_, out);
}

// Round 2
// 1407.987 us; speedup vs baseline: 1.2734x; 1.0463x over previous
//
#include <hip/hip_runtime.h>
#include <hip/hip_bf16.h>
#include <stdint.h>

// Problem constants (B,S,H,L) = (8, 4096, 2048, 4)
#define B_ 8
#define S_ 4096
#define H_ 2048
#define L_ 4
#define M_ (B_ * S_)   // 32768 rows
// GEMM: C[M,N] = A[M,K] * W[N,K]^T + bias, K = N = H_

typedef __attribute__((ext_vector_type(8))) __bf16 bf16x8;
typedef __attribute__((ext_vector_type(4))) float f32x4;

__device__ __forceinline__ unsigned short f32_bf16_rne(float f) {
    union { float f; unsigned int u; } v;
    v.f = f;
    unsigned int u = v.u;
    u += 0x7FFFu + ((u >> 16) & 1u);   // round-to-nearest-even
    return (unsigned short)(u >> 16);
}

__global__ void cvt_f32_to_bf16(const float4* __restrict__ in,
                                ushort4* __restrict__ out, int n4) {
    int i = blockIdx.x * blockDim.x + threadIdx.x;
    if (i < n4) {
        float4 v = in[i];
        ushort4 o;
        o.x = f32_bf16_rne(v.x);
        o.y = f32_bf16_rne(v.y);
        o.z = f32_bf16_rne(v.z);
        o.w = f32_bf16_rne(v.w);
        out[i] = o;
    }
}

// ---------------------------------------------------------------------------
// 256x256-tile, BK=64, 8-wave (2M x 4N), 8-phase schedule with counted vmcnt
// (T1 XCD swizzle + T2 LDS XOR swizzle + T3/T4 phases + T5 setprio).
//
// LDS: [buf(2)][mat A/B][256 rows][64 k] bf16 = 128 KiB. Half-tile = 128 rows.
// Staging: global_load_lds width=16, linear LDS dest (wave base + lane*16B).
//   Swizzle is applied by permuting the per-lane GLOBAL source column-chunk
//   (j ^= row&7 at 16B granularity) and the same XOR on the ds_read side.
// Schedule per K-tile kt (4 phases, each: ds_read subtile | stage 1 half |
//   s_barrier | lgkmcnt(0) | setprio(1) 16xMFMA setprio(0) | s_barrier):
//   ph0: read B(all)+A(f0,f1); stage A-lo(kt+1)
//   ph1: read A(f2,f3);        stage A-hi(kt+1), B-lo(kt+2)
//   ph2: read A(f4,f5);        stage B-hi(kt+2)
//   ph3: read A(f6,f7);        fence vmcnt(4) AFTER the MFMA cluster
//                              (A(kt+1) first read after ph3's 2nd barrier,
//                               so the fence hides under MFMA_Q(3))
// ---------------------------------------------------------------------------

#define GLDS(srcp, dstp)                                                      \
    __builtin_amdgcn_global_load_lds(                                         \
        (const __attribute__((address_space(1))) void*)(srcp),                \
        (__attribute__((address_space(3))) void*)(dstp), 16, 0, 0)

template <bool OUT_BF16>
__global__ __launch_bounds__(512, 2)
void gemm8(const unsigned short* __restrict__ A,   // M x K, bf16 bits
           const unsigned short* __restrict__ W,   // N x K, bf16 bits
           const float* __restrict__ bias,         // N
           const int* __restrict__ perm,           // S_ entries or nullptr
           void* __restrict__ outv)                // M x N
{
    constexpr int K = H_;
    constexpr int N = H_;

    __shared__ unsigned short lds[65536];  // 128 KiB

    const int tid = threadIdx.x;
    const int w   = tid >> 6;     // wave 0..7
    const int l   = tid & 63;

    // T1: XCD-aware swizzle, A-reuse oriented. XCD x (= bid&7) owns the
    // contiguous tileM chunk [x*16, x*16+16) with tileN varying FASTEST:
    // the 32 co-resident blocks per XCD share 4 A-panels (8 readers each, all
    // on the same L2), so each A-panel is fetched from HBM once. W (8 MB
    // total) is L3/L2-resident regardless. (Round-1 mapping had tileN==XCD,
    // which fetched every A-panel into 8 different L2s: FETCH 541 MB vs ~136
    // ideal, and the L2-missing A loads stalled the per-K-tile vmcnt fence.)
    const int bid   = blockIdx.x;
    const int wgid  = (bid & 7) * 128 + (bid >> 3);
    const int tileN = wgid & 7;    // fastest within XCD
    const int tileM = wgid >> 3;   // [x*16, x*16+16) on XCD x

    // ---- staging source pointers (per half h, per issue i) ----
    // LDS chunk (row, j') holds global col-chunk j'^(row&7); with linear dest
    // chunk = (i*8+w)*64 + l we get row&7 == (l>>3)&7, so the source column
    // chunk is the lane constant (l&7)^((l>>3)&7).
    const int jsrc = (l & 7) ^ ((l >> 3) & 7);
    const unsigned short* aP[2][2];
    const unsigned short* bP[2][2];
#pragma unroll
    for (int h = 0; h < 2; ++h)
#pragma unroll
        for (int i = 0; i < 2; ++i) {
            int r  = h * 128 + (i * 8 + w) * 8 + (l >> 3);  // row in 256-tile
            int gm = tileM * 256 + r;
            int src;
            if (perm) {
                int b = gm >> 12;            // / S_
                int s = gm & (S_ - 1);
                src = (b << 12) + perm[s];   // gather source row
            } else {
                src = gm;
            }
            aP[h][i] = A + (size_t)src * K + jsrc * 8;
            bP[h][i] = W + (size_t)(tileN * 256 + r) * K + jsrc * 8;
        }

    unsigned short* ldsw = &lds[w * 512];  // wave-uniform dest base

#define STAGE_A(buf, half, kt0) do {                                          \
        GLDS(aP[half][0] + (kt0) * 64,                                        \
             ldsw + (buf) * 32768 + (half) * 8192);                           \
        GLDS(aP[half][1] + (kt0) * 64,                                        \
             ldsw + (buf) * 32768 + (half) * 8192 + 4096);                    \
    } while (0)
#define STAGE_B(buf, half, kt0) do {                                          \
        GLDS(bP[half][0] + (kt0) * 64,                                        \
             ldsw + (buf) * 32768 + 16384 + (half) * 8192);                   \
        GLDS(bP[half][1] + (kt0) * 64,                                        \
             ldsw + (buf) * 32768 + 16384 + (half) * 8192 + 4096);            \
    } while (0)

    // ---- fragment read addressing (T2 read-side XOR) ----
    const int lm = l & 15;
    const int wm = w >> 2;   // 0..1  M-half of tile
    const int wn = w & 3;    // 0..3  N-quarter of tile
    const int cx0 = (((l >> 4) + 0) ^ (l & 7)) * 8;   // swizzled col, ks=0
    const int cx1 = (((l >> 4) + 4) ^ (l & 7)) * 8;   // swizzled col, ks=1
    const int aO0 = (wm * 128 + lm) * 64 + cx0;
    const int aO1 = (wm * 128 + lm) * 64 + cx1;
    const int bO0 = 16384 + (wn * 64 + lm) * 64 + cx0;
    const int bO1 = 16384 + (wn * 64 + lm) * 64 + cx1;

#define LDA(bo, f, ks) (*(const bf16x8*)&lds[(bo) + ((ks) ? aO1 : aO0) + (f) * 1024])
#define LDB(bo, n, ks) (*(const bf16x8*)&lds[(bo) + ((ks) ? bO1 : bO0) + (n) * 1024])

    f32x4 acc[8][4];
#pragma unroll
    for (int i = 0; i < 8; ++i)
#pragma unroll
        for (int j2 = 0; j2 < 4; ++j2) {
            f32x4 z = {0.f, 0.f, 0.f, 0.f};
            acc[i][j2] = z;
        }

    // ---- prologue: K-tile 0 (4 halves) -> buf0; B of K-tile 1 -> buf1 ----
    STAGE_A(0, 0, 0); STAGE_A(0, 1, 0);
    STAGE_B(0, 0, 0); STAGE_B(0, 1, 0);
    STAGE_B(1, 0, 1); STAGE_B(1, 1, 1);
    asm volatile("s_waitcnt vmcnt(4)" ::: "memory");  // K-tile 0 resident
    __builtin_amdgcn_s_barrier();

#define MFMA_Q(q)                                                             \
    __builtin_amdgcn_s_setprio(1);                                            \
    _Pragma("unroll")                                                         \
    for (int n = 0; n < 4; ++n) {                                             \
        acc[2*(q)  ][n] = __builtin_amdgcn_mfma_f32_16x16x32_bf16(            \
            a0k0, bf[n][0], acc[2*(q)  ][n], 0, 0, 0);                        \
        acc[2*(q)  ][n] = __builtin_amdgcn_mfma_f32_16x16x32_bf16(            \
            a0k1, bf[n][1], acc[2*(q)  ][n], 0, 0, 0);                        \
        acc[2*(q)+1][n] = __builtin_amdgcn_mfma_f32_16x16x32_bf16(            \
            a1k0, bf[n][0], acc[2*(q)+1][n], 0, 0, 0);                        \
        acc[2*(q)+1][n] = __builtin_amdgcn_mfma_f32_16x16x32_bf16(            \
            a1k1, bf[n][1], acc[2*(q)+1][n], 0, 0, 0);                        \
    }                                                                         \
    __builtin_amdgcn_s_setprio(0);

    for (int kt = 0; kt < 32; ++kt) {
        const int bo = (kt & 1) << 15;   // current buffer, element offset
        const int cb = kt & 1;
        const int nb = cb ^ 1;
        bf16x8 bf[4][2];

        { // phase 0: B frags + A f0,f1; stage A-lo(kt+1)
            bf16x8 a0k0 = LDA(bo, 0, 0), a0k1 = LDA(bo, 0, 1);
            bf16x8 a1k0 = LDA(bo, 1, 0), a1k1 = LDA(bo, 1, 1);
#pragma unroll
            for (int n = 0; n < 4; ++n) {
                bf[n][0] = LDB(bo, n, 0);
                bf[n][1] = LDB(bo, n, 1);
            }
            if (kt < 31) STAGE_A(nb, 0, kt + 1);
            __builtin_amdgcn_s_barrier();
            asm volatile("s_waitcnt lgkmcnt(0)" ::: "memory");
            MFMA_Q(0);
            __builtin_amdgcn_s_barrier();
        }
        { // phase 1: A f2,f3; stage A-hi(kt+1), B-lo(kt+2)
            bf16x8 a0k0 = LDA(bo, 2, 0), a0k1 = LDA(bo, 2, 1);
            bf16x8 a1k0 = LDA(bo, 3, 0), a1k1 = LDA(bo, 3, 1);
            if (kt < 31) STAGE_A(nb, 1, kt + 1);
            if (kt < 30) STAGE_B(cb, 0, kt + 2);
            __builtin_amdgcn_s_barrier();
            asm volatile("s_waitcnt lgkmcnt(0)" ::: "memory");
            MFMA_Q(1);
            __builtin_amdgcn_s_barrier();
        }
        { // phase 2: A f4,f5; stage B-hi(kt+2)
            bf16x8 a0k0 = LDA(bo, 4, 0), a0k1 = LDA(bo, 4, 1);
            bf16x8 a1k0 = LDA(bo, 5, 0), a1k1 = LDA(bo, 5, 1);
            if (kt < 30) STAGE_B(cb, 1, kt + 2);
            __builtin_amdgcn_s_barrier();
            asm volatile("s_waitcnt lgkmcnt(0)" ::: "memory");
            MFMA_Q(2);
            __builtin_amdgcn_s_barrier();
        }
        { // phase 3: A f6,f7; counted fence AFTER the MFMA cluster.
          // A(kt+1) is first read after this phase's 2nd barrier, so the
          // vmcnt wait overlaps MFMA_Q(3) instead of stalling before it.
            bf16x8 a0k0 = LDA(bo, 6, 0), a0k1 = LDA(bo, 6, 1);
            bf16x8 a1k0 = LDA(bo, 7, 0), a1k1 = LDA(bo, 7, 1);
            __builtin_amdgcn_s_barrier();
            asm volatile("s_waitcnt lgkmcnt(0)" ::: "memory");
            MFMA_Q(3);
            if (kt < 30) {
                asm volatile("s_waitcnt vmcnt(4)" ::: "memory");
            } else if (kt == 30) {
                asm volatile("s_waitcnt vmcnt(0)" ::: "memory");
            }
            __builtin_amdgcn_s_barrier();
        }
    }

    // ---- epilogue: C/D layout col = lane&15, row = (lane>>4)*4 + reg ----
    const int orow0 = tileM * 256 + wm * 128 + (l >> 4) * 4;
    const int ocol0 = tileN * 256 + wn * 64 + lm;
    float bval[4];
#pragma unroll
    for (int n = 0; n < 4; ++n) bval[n] = bias[ocol0 + n * 16];

#pragma unroll
    for (int f = 0; f < 8; ++f) {
#pragma unroll
        for (int n = 0; n < 4; ++n) {
#pragma unroll
            for (int r = 0; r < 4; ++r) {
                int row = orow0 + f * 16 + r;
                int col = ocol0 + n * 16;
                float v = acc[f][n][r] + bval[n];
                if (OUT_BF16) {
                    ((unsigned short*)outv)[(size_t)row * N + col] = f32_bf16_rne(v);
                } else {
                    ((float*)outv)[(size_t)row * N + col] = v;
                }
            }
        }
    }
#undef LDA
#undef LDB
#undef STAGE_A
#undef STAGE_B
#undef MFMA_Q
}

extern "C" void kernel_launch(void* const* d_in, const int* in_sizes, int n_in,
                              void* d_out, int out_size, void* d_ws, size_t ws_size,
                              hipStream_t stream) {
    const float* x       = (const float*)d_in[0];  // (8,4096,2048) f32
    const float* weights = (const float*)d_in[1];  // (4,2048,2048) f32
    const float* biases  = (const float*)d_in[2];  // (4,2048) f32
    const int*   perms   = (const int*)d_in[3];    // (3,4096) i32
    float* out = (float*)d_out;

    // ws layout: P = bf16 ping buffer (128 MB), Wbf = bf16 weights (32 MB).
    // Q = low half of d_out reinterpreted as bf16 (d_out is 256 MB fp32).
    // Sequence Q -> P -> Q -> P -> d_out keeps final-layer input (P) disjoint
    // from its fp32 output (d_out).
    unsigned short* bufP = (unsigned short*)d_ws;
    unsigned short* wBf  = (unsigned short*)((char*)d_ws + (size_t)M_ * H_ * 2);
    unsigned short* bufQ = (unsigned short*)d_out;

    {
        int n4 = (L_ * H_ * H_) / 4;
        cvt_f32_to_bf16<<<(n4 + 255) / 256, 256, 0, stream>>>(
            (const float4*)weights, (ushort4*)wBf, n4);
    }
    {
        int n4 = (M_ * H_) / 4;
        cvt_f32_to_bf16<<<(n4 + 255) / 256, 256, 0, stream>>>(
            (const float4*)x, (ushort4*)bufQ, n4);
    }

    dim3 grid(1024);  // (M_/256) * (H_/256) = 128 * 8
    // layer 0: no gather
    gemm8<true ><<<grid, 512, 0, stream>>>(bufQ, wBf + 0 * (size_t)H_ * H_,
                                           biases + 0 * H_, nullptr, bufP);
    // layer 1: gather rows via perms[0]
    gemm8<true ><<<grid, 512, 0, stream>>>(bufP, wBf + 1 * (size_t)H_ * H_,
                                           biases + 1 * H_, perms + 0 * S_, bufQ);
    // layer 2: gather via perms[1]
    gemm8<true ><<<grid, 512, 0, stream>>>(bufQ, wBf + 2 * (size_t)H_ * H_,
                                           biases + 2 * H_, perms + 1 * S_, bufP);
    // layer 3: gather via perms[2], fp32 output
    gemm8<false><<<grid, 512, 0, stream>>>(bufP, wBf + 3 * (size_t)H_ * H_,
                                           biases + 3 * H_, perms + 2 * S_, out);
}